// Round 1
// baseline (348.286 us; speedup 1.0000x reference)
//
#include <hip/hip_runtime.h>

typedef __attribute__((ext_vector_type(4))) float f32x4;
typedef __attribute__((ext_vector_type(8))) __bf16 bf16x8;
typedef __attribute__((ext_vector_type(4))) short s16x4;

#define DEVI static __device__ __forceinline__

#define LOG2E 1.44269504088896340736f

// float -> bf16 (RNE), finite inputs
DEVI short f2bf(float f) {
  unsigned u = __builtin_bit_cast(unsigned, f);
  unsigned r = (u + 0x7fffu + ((u >> 16) & 1u)) >> 16;
  return (short)r;
}

// async global->LDS, 16B per lane; dest = uniform base + lane*16
DEVI void gll16(const short* gsrc, short* ldst) {
  __builtin_amdgcn_global_load_lds(
      (const __attribute__((address_space(1))) unsigned*)gsrc,
      (__attribute__((address_space(3))) unsigned*)ldst, 16, 0, 0);
}

// Stage one 1KB chunk (64 granules of 16B) of a [rows][64-short] LDS tile.
// LDS granule q holds global chunk k8 = (q&7) ^ (row&7) of row q>>3
// (pre-swizzled source, linear LDS dest — m173 pattern; conflict-free reads).
DEVI void stage_gran(const short* g, int ldRow, short* lds, int p, int lane) {
  int q = p + lane;
  int row = q >> 3;
  int k8 = (q & 7) ^ (row & 7);
  gll16(g + (size_t)row * ldRow + k8 * 8, lds + (size_t)p * 8);
}

// Read a 16x32 MFMA operand fragment from a swizzled tile.
// base = start of 16-row block (rowblk*64 shorts, rowblk % 16 == 0).
// lane&15 = row-in-block (M/N index), k-chunk = kk*4 + (lane>>4).
DEVI bf16x8 frag_ld(const short* base, int lane, int kk) {
  int r = lane & 15;
  int chunk = (kk * 4 + (lane >> 4)) ^ (r & 7);
  return *(const bf16x8*)(base + r * 64 + chunk * 8);
}

// ---------------- converts ----------------

__global__ void cvt_k(const float* __restrict__ in, short* __restrict__ out, int n4) {
  int i = blockIdx.x * blockDim.x + threadIdx.x;
  if (i < n4) {
    f32x4 v = *(const f32x4*)(in + (size_t)i * 4);
    s16x4 o;
    #pragma unroll
    for (int j = 0; j < 4; ++j) o[j] = f2bf(v[j]);
    *(s16x4*)(out + (size_t)i * 4) = o;
  }
}

// transpose + convert: in fp32 [R][C] -> out bf16 [C][R]
__global__ void tcvt_k(const float* __restrict__ in, short* __restrict__ out, int R, int C) {
  __shared__ float t[32][33];
  const int bx = blockIdx.x * 32;   // C offset
  const int by = blockIdx.y * 32;   // R offset
  const int lx = threadIdx.x & 31, ly = threadIdx.x >> 5;
  #pragma unroll
  for (int rr = ly; rr < 32; rr += 8)
    t[rr][lx] = in[(size_t)(by + rr) * C + bx + lx];
  __syncthreads();
  #pragma unroll
  for (int cc = ly; cc < 32; cc += 8)
    out[(size_t)(bx + cc) * R + by + lx] = f2bf(t[lx][cc]);
}

// ---------------- GEMM: C[M][N] = A[M][K] @ Bt[N][K]^T + bias ----------------
// EPI 0: scatter to Q (scaled), K, V^T bf16 per-head buffers.
// EPI 1: fp32 output [M][N].

template <int EPI>
__global__ __launch_bounds__(256, 3)
void gemm_k(const short* __restrict__ A, const short* __restrict__ Bt,
            const float* __restrict__ bias, float* __restrict__ outF,
            short* __restrict__ Qb, short* __restrict__ Kb, short* __restrict__ Vtb,
            int M, int N, int K) {
  __shared__ __align__(16) short As[128 * 64];
  __shared__ __align__(16) short Bs[128 * 64];
  const int lane = threadIdx.x & 63;
  const int wid  = threadIdx.x >> 6;
  const int mt = blockIdx.x * 128;
  const int nt = blockIdx.y * 128;
  const int wm = (wid >> 1) * 64;
  const int wn = (wid & 1) * 64;

  f32x4 acc[4][4];
  #pragma unroll
  for (int i = 0; i < 4; ++i)
    #pragma unroll
    for (int j = 0; j < 4; ++j) acc[i][j] = (f32x4){0.f, 0.f, 0.f, 0.f};

  const short* Atile = A + (size_t)mt * K;
  const short* Btile = Bt + (size_t)nt * K;
  const int nkt = K >> 6;

  for (int kt = 0; kt < nkt; ++kt) {
    __syncthreads();
    #pragma unroll
    for (int i = 0; i < 4; ++i) {
      stage_gran(Atile + kt * 64, K, As, (wid * 4 + i) * 64, lane);
      stage_gran(Btile + kt * 64, K, Bs, (wid * 4 + i) * 64, lane);
    }
    __syncthreads();
    #pragma unroll
    for (int kk = 0; kk < 2; ++kk) {
      bf16x8 af[4], bfr[4];
      #pragma unroll
      for (int i = 0; i < 4; ++i) af[i] = frag_ld(As + (wm + i * 16) * 64, lane, kk);
      #pragma unroll
      for (int j = 0; j < 4; ++j) bfr[j] = frag_ld(Bs + (wn + j * 16) * 64, lane, kk);
      #pragma unroll
      for (int i = 0; i < 4; ++i)
        #pragma unroll
        for (int j = 0; j < 4; ++j)
          acc[i][j] = __builtin_amdgcn_mfma_f32_16x16x32_bf16(af[i], bfr[j], acc[i][j], 0, 0, 0);
    }
  }

  const int rbase = (lane >> 4) * 4;
  const int cl = lane & 15;
  #pragma unroll
  for (int i = 0; i < 4; ++i) {
    #pragma unroll
    for (int j = 0; j < 4; ++j) {
      const int col = nt + wn + j * 16 + cl;
      const float bv = bias[col];
      #pragma unroll
      for (int r = 0; r < 4; ++r) {
        const int row = mt + wm + i * 16 + rbase + r;
        float v = acc[i][j][r] + bv;
        if (EPI == 1) {
          outF[(size_t)row * N + col] = v;
        } else {
          const int which = col >> 9;  // 0=Q 1=K 2=V
          const int d = col & 511;
          const int h = d >> 6, hd = d & 63;
          const int b = row >> 12, n = row & 4095;
          const int bh = b * 8 + h;
          if (which == 0)
            Qb[((size_t)bh * 4096 + n) * 64 + hd] = f2bf(v * (0.125f * LOG2E));
          else if (which == 1)
            Kb[((size_t)bh * 4096 + n) * 64 + hd] = f2bf(v);
          else
            Vtb[((size_t)bh * 64 + hd) * 4096 + n] = f2bf(v);
        }
      }
    }
  }
}

// ---------------- flash attention ----------------
// grid (N/128, BH); 4 waves, each owns 32 q-rows. Q pre-scaled by 0.125*log2e.

__global__ __launch_bounds__(256, 2)
void attn_k(const short* __restrict__ Qb, const short* __restrict__ Kb,
            const short* __restrict__ Vtb, short* __restrict__ AOut) {
  __shared__ __align__(16) short Ks[64 * 64];     // [kv][d]  swizzled
  __shared__ __align__(16) short Vs[64 * 64];     // [d][kv]  swizzled
  __shared__ __align__(16) short Ps[4][32 * 64];  // per-wave P [q][kv] swizzled
  const int lane = threadIdx.x & 63;
  const int wid = threadIdx.x >> 6;
  const int bh = blockIdx.y;
  const int qt = blockIdx.x * 128 + wid * 32;
  const short* Qh = Qb + (size_t)bh * 4096 * 64;
  const short* Kh = Kb + (size_t)bh * 4096 * 64;
  const short* Vh = Vtb + (size_t)bh * 64 * 4096;
  const int cl = lane & 15, g = lane >> 4;

  bf16x8 qf[2][2];
  #pragma unroll
  for (int i = 0; i < 2; ++i)
    #pragma unroll
    for (int kd = 0; kd < 2; ++kd)
      qf[i][kd] = *(const bf16x8*)(Qh + (size_t)(qt + i * 16 + cl) * 64 + kd * 32 + g * 8);

  f32x4 o[2][4];
  #pragma unroll
  for (int i = 0; i < 2; ++i)
    #pragma unroll
    for (int jd = 0; jd < 4; ++jd) o[i][jd] = (f32x4){0.f, 0.f, 0.f, 0.f};
  float mrow[2][4], lrow[2][4];
  #pragma unroll
  for (int i = 0; i < 2; ++i)
    #pragma unroll
    for (int r = 0; r < 4; ++r) { mrow[i][r] = -1e30f; lrow[i][r] = 0.f; }

  for (int kv = 0; kv < 4096; kv += 64) {
    __syncthreads();
    #pragma unroll
    for (int t = 0; t < 2; ++t) {
      stage_gran(Kh + (size_t)kv * 64, 64, Ks, (wid * 2 + t) * 64, lane);
      stage_gran(Vh + kv, 4096, Vs, (wid * 2 + t) * 64, lane);
    }
    __syncthreads();

    // S = Q K^T  (in exp2 domain)
    f32x4 s[2][4];
    #pragma unroll
    for (int i = 0; i < 2; ++i)
      #pragma unroll
      for (int j = 0; j < 4; ++j) s[i][j] = (f32x4){0.f, 0.f, 0.f, 0.f};
    #pragma unroll
    for (int kd = 0; kd < 2; ++kd) {
      bf16x8 kf[4];
      #pragma unroll
      for (int j = 0; j < 4; ++j) kf[j] = frag_ld(Ks + j * 16 * 64, lane, kd);
      #pragma unroll
      for (int i = 0; i < 2; ++i)
        #pragma unroll
        for (int j = 0; j < 4; ++j)
          s[i][j] = __builtin_amdgcn_mfma_f32_16x16x32_bf16(qf[i][kd], kf[j], s[i][j], 0, 0, 0);
    }

    // online softmax; row = i*16 + g*4 + r, cols spread over j and lane&15
    #pragma unroll
    for (int i = 0; i < 2; ++i) {
      #pragma unroll
      for (int r = 0; r < 4; ++r) {
        float mx = fmaxf(fmaxf(s[i][0][r], s[i][1][r]), fmaxf(s[i][2][r], s[i][3][r]));
        #pragma unroll
        for (int d = 1; d < 16; d <<= 1) mx = fmaxf(mx, __shfl_xor(mx, d));
        float mnew = fmaxf(mrow[i][r], mx);
        float corr = exp2f(mrow[i][r] - mnew);
        mrow[i][r] = mnew;
        float rs = 0.f;
        #pragma unroll
        for (int j = 0; j < 4; ++j) {
          float p = exp2f(s[i][j][r] - mnew);
          s[i][j][r] = p;
          rs += p;
        }
        #pragma unroll
        for (int d = 1; d < 16; d <<= 1) rs += __shfl_xor(rs, d);
        lrow[i][r] = lrow[i][r] * corr + rs;
        #pragma unroll
        for (int jd = 0; jd < 4; ++jd) o[i][jd][r] *= corr;
      }
    }

    // P -> bf16 -> per-wave swizzled LDS
    short* P = (short*)Ps[wid];
    #pragma unroll
    for (int i = 0; i < 2; ++i)
      #pragma unroll
      for (int j = 0; j < 4; ++j)
        #pragma unroll
        for (int r = 0; r < 4; ++r) {
          int prow = i * 16 + g * 4 + r;
          int pcol = j * 16 + cl;
          int chunk = (pcol >> 3) ^ (prow & 7);
          P[prow * 64 + chunk * 8 + (pcol & 7)] = f2bf(s[i][j][r]);
        }

    // O += P @ V
    #pragma unroll
    for (int kk = 0; kk < 2; ++kk) {
      bf16x8 pf[2], vf[4];
      #pragma unroll
      for (int i = 0; i < 2; ++i) pf[i] = frag_ld(P + i * 16 * 64, lane, kk);
      #pragma unroll
      for (int jd = 0; jd < 4; ++jd) vf[jd] = frag_ld(Vs + jd * 16 * 64, lane, kk);
      #pragma unroll
      for (int i = 0; i < 2; ++i)
        #pragma unroll
        for (int jd = 0; jd < 4; ++jd)
          o[i][jd] = __builtin_amdgcn_mfma_f32_16x16x32_bf16(pf[i], vf[jd], o[i][jd], 0, 0, 0);
    }
  }

  // epilogue: O/l -> attn_out bf16 [b][n][h*64+d]
  const int b = bh >> 3, h = bh & 7;
  #pragma unroll
  for (int i = 0; i < 2; ++i) {
    #pragma unroll
    for (int r = 0; r < 4; ++r) {
      const float inv = 1.f / lrow[i][r];
      const int n = qt + i * 16 + g * 4 + r;
      #pragma unroll
      for (int jd = 0; jd < 4; ++jd) {
        const int d = h * 64 + jd * 16 + cl;
        AOut[((size_t)b * 4096 + n) * 512 + d] = f2bf(o[i][jd][r] * inv);
      }
    }
  }
}

// ---------------- launcher ----------------

extern "C" void kernel_launch(void* const* d_in, const int* in_sizes, int n_in,
                              void* d_out, int out_size, void* d_ws, size_t ws_size,
                              hipStream_t stream) {
  const float* x    = (const float*)d_in[0];
  const float* Wqkv = (const float*)d_in[1];
  const float* bqkv = (const float*)d_in[2];
  const float* Wout = (const float*)d_in[3];
  const float* bout = (const float*)d_in[4];
  float* out = (float*)d_out;

  short* ws   = (short*)d_ws;
  short* xb   = ws;                       // 8192*512
  short* Wqt  = xb + 8192 * 512;          // 1536*512  (W_qkv^T)
  short* Wot  = Wqt + 1536 * 512;         // 512*512   (W_out^T)
  short* Qb   = Wot + 512 * 512;          // 16*4096*64 (scaled)
  short* Kb   = Qb + 16 * 4096 * 64;
  short* Vtb  = Kb + 16 * 4096 * 64;      // per-head V^T [bh][64][4096]
  short* AOut = Vtb + 16 * 4096 * 64;     // 8192*512

  hipLaunchKernelGGL(cvt_k, dim3(8192 * 512 / 4 / 256), dim3(256), 0, stream,
                     x, xb, 8192 * 512 / 4);
  hipLaunchKernelGGL(tcvt_k, dim3(1536 / 32, 512 / 32), dim3(256), 0, stream,
                     Wqkv, Wqt, 512, 1536);
  hipLaunchKernelGGL(tcvt_k, dim3(512 / 32, 512 / 32), dim3(256), 0, stream,
                     Wout, Wot, 512, 512);
  hipLaunchKernelGGL(gemm_k<0>, dim3(8192 / 128, 1536 / 128), dim3(256), 0, stream,
                     xb, Wqt, bqkv, (float*)nullptr, Qb, Kb, Vtb, 8192, 1536, 512);
  hipLaunchKernelGGL(attn_k, dim3(4096 / 128, 16), dim3(256), 0, stream,
                     Qb, Kb, Vtb, AOut);
  hipLaunchKernelGGL(gemm_k<1>, dim3(8192 / 128, 512 / 128), dim3(256), 0, stream,
                     AOut, Wot, bout, out, (short*)nullptr, (short*)nullptr, (short*)nullptr,
                     8192, 512, 512);
}

// Round 4
// 250.964 us; speedup vs baseline: 1.3878x; 1.3878x over previous
//
#include <hip/hip_runtime.h>

typedef __attribute__((ext_vector_type(4))) float f32x4;
typedef __attribute__((ext_vector_type(8))) __bf16 bf16x8;
typedef __attribute__((ext_vector_type(4))) __bf16 bf16x4;
typedef __attribute__((ext_vector_type(4))) short s16x4;

#define DEVI static __device__ __forceinline__

#define LOG2E 1.44269504088896340736f
#define THR 10.0f

// float -> bf16 (RNE) via hardware cvt
DEVI short f2bf(float f) {
  return __builtin_bit_cast(short, (__bf16)f);
}

// async global->LDS, 16B per lane; dest = uniform base + lane*16
DEVI void gll16(const short* gsrc, short* ldst) {
  __builtin_amdgcn_global_load_lds(
      (const __attribute__((address_space(1))) unsigned*)gsrc,
      (__attribute__((address_space(3))) unsigned*)ldst, 16, 0, 0);
}

// Stage one 1KB chunk (64 granules of 16B) of a [rows][64-short] LDS tile.
// LDS granule q holds global chunk k8 = (q&7) ^ (row&7) of row q>>3
// (pre-swizzled source, linear LDS dest — conflict-free swizzled reads).
DEVI void stage_gran(const short* g, int ldRow, short* lds, int p, int lane) {
  int q = p + lane;
  int row = q >> 3;
  int k8 = (q & 7) ^ (row & 7);
  gll16(g + (size_t)row * ldRow + k8 * 8, lds + (size_t)p * 8);
}

// Read a 16x32 MFMA operand fragment from a swizzled tile.
// lane&15 = row-in-block (M/N index), k-chunk = kk*4 + (lane>>4).
DEVI bf16x8 frag_ld(const short* base, int lane, int kk) {
  int r = lane & 15;
  int chunk = (kk * 4 + (lane >> 4)) ^ (r & 7);
  return *(const bf16x8*)(base + r * 64 + chunk * 8);
}

// ---------------- converts ----------------

__global__ void cvt_k(const float* __restrict__ in, short* __restrict__ out, int n4) {
  int i = blockIdx.x * blockDim.x + threadIdx.x;
  if (i < n4) {
    f32x4 v = *(const f32x4*)(in + (size_t)i * 4);
    s16x4 o;
    #pragma unroll
    for (int j = 0; j < 4; ++j) o[j] = f2bf(v[j]);
    *(s16x4*)(out + (size_t)i * 4) = o;
  }
}

// transpose + convert: in fp32 [R][C] -> out bf16 [C][R]
__global__ void tcvt_k(const float* __restrict__ in, short* __restrict__ out, int R, int C) {
  __shared__ float t[32][33];
  const int bx = blockIdx.x * 32;   // C offset
  const int by = blockIdx.y * 32;   // R offset
  const int lx = threadIdx.x & 31, ly = threadIdx.x >> 5;
  #pragma unroll
  for (int rr = ly; rr < 32; rr += 8)
    t[rr][lx] = in[(size_t)(by + rr) * C + bx + lx];
  __syncthreads();
  #pragma unroll
  for (int cc = ly; cc < 32; cc += 8)
    out[(size_t)(bx + cc) * R + by + lx] = f2bf(t[lx][cc]);
}

// ---------------- GEMM: C[M][N] = A[M][K] @ Bt[N][K]^T + bias ----------------

template <int EPI>
__global__ __launch_bounds__(256, 3)
void gemm_k(const short* __restrict__ A, const short* __restrict__ Bt,
            const float* __restrict__ bias, float* __restrict__ outF,
            short* __restrict__ Qb, short* __restrict__ Kb, short* __restrict__ Vtb,
            int M, int N, int K) {
  __shared__ __align__(16) short As[128 * 64];
  __shared__ __align__(16) short Bs[128 * 64];
  const int lane = threadIdx.x & 63;
  const int wid  = threadIdx.x >> 6;
  const int mt = blockIdx.x * 128;
  const int nt = blockIdx.y * 128;
  const int wm = (wid >> 1) * 64;
  const int wn = (wid & 1) * 64;

  f32x4 acc[4][4];
  #pragma unroll
  for (int i = 0; i < 4; ++i)
    #pragma unroll
    for (int j = 0; j < 4; ++j) acc[i][j] = (f32x4){0.f, 0.f, 0.f, 0.f};

  const short* Atile = A + (size_t)mt * K;
  const short* Btile = Bt + (size_t)nt * K;
  const int nkt = K >> 6;

  for (int kt = 0; kt < nkt; ++kt) {
    __syncthreads();
    #pragma unroll
    for (int i = 0; i < 4; ++i) {
      stage_gran(Atile + kt * 64, K, As, (wid * 4 + i) * 64, lane);
      stage_gran(Btile + kt * 64, K, Bs, (wid * 4 + i) * 64, lane);
    }
    __syncthreads();
    #pragma unroll
    for (int kk = 0; kk < 2; ++kk) {
      bf16x8 af[4], bfr[4];
      #pragma unroll
      for (int i = 0; i < 4; ++i) af[i] = frag_ld(As + (wm + i * 16) * 64, lane, kk);
      #pragma unroll
      for (int j = 0; j < 4; ++j) bfr[j] = frag_ld(Bs + (wn + j * 16) * 64, lane, kk);
      #pragma unroll
      for (int i = 0; i < 4; ++i)
        #pragma unroll
        for (int j = 0; j < 4; ++j)
          acc[i][j] = __builtin_amdgcn_mfma_f32_16x16x32_bf16(af[i], bfr[j], acc[i][j], 0, 0, 0);
    }
  }

  const int rbase = (lane >> 4) * 4;
  const int cl = lane & 15;
  #pragma unroll
  for (int i = 0; i < 4; ++i) {
    #pragma unroll
    for (int j = 0; j < 4; ++j) {
      const int col = nt + wn + j * 16 + cl;
      const float bv = bias[col];
      #pragma unroll
      for (int r = 0; r < 4; ++r) {
        const int row = mt + wm + i * 16 + rbase + r;
        float v = acc[i][j][r] + bv;
        if (EPI == 1) {
          outF[(size_t)row * N + col] = v;
        } else {
          const int which = col >> 9;  // 0=Q 1=K 2=V
          const int d = col & 511;
          const int h = d >> 6, hd = d & 63;
          const int b = row >> 12, n = row & 4095;
          const int bh = b * 8 + h;
          if (which == 0)
            Qb[((size_t)bh * 4096 + n) * 64 + hd] = f2bf(v * (0.125f * LOG2E));
          else if (which == 1)
            Kb[((size_t)bh * 4096 + n) * 64 + hd] = f2bf(v);
          else
            Vtb[((size_t)bh * 64 + hd) * 4096 + n] = f2bf(v);
        }
      }
    }
  }
}

// ---------------- flash attention (swapped QK^T, in-register softmax) -------
// grid (N/128, BH); 4 waves, each owns 32 q-rows. Q pre-scaled by 0.125*log2e.
// QK^T computed as mfma(K_frag, Q_frag) -> C[kv][q]: each lane holds, for one
// q-row (cl), 4 consecutive kv per (j, reg). Row-sum via ones-MFMA; defer-max.

__global__ __launch_bounds__(256, 2)
void attn_k(const short* __restrict__ Qb, const short* __restrict__ Kb,
            const short* __restrict__ Vtb, short* __restrict__ AOut) {
  __shared__ __align__(16) short Ks[64 * 64];     // [kv][d]  swizzled
  __shared__ __align__(16) short Vs[64 * 64];     // [d][kv]  swizzled
  __shared__ __align__(16) short Ps[4][32 * 64];  // per-wave P [q][kv] swizzled
  const int lane = threadIdx.x & 63;
  const int wid = threadIdx.x >> 6;
  const int bh = blockIdx.y;
  const int qt = blockIdx.x * 128 + wid * 32;
  const short* Qh = Qb + (size_t)bh * 4096 * 64;
  const short* Kh = Kb + (size_t)bh * 4096 * 64;
  const short* Vh = Vtb + (size_t)bh * 64 * 4096;
  const int cl = lane & 15, g = lane >> 4;

  // Q fragments (B-operand of swapped QK^T): lane&15 = q-row
  bf16x8 qf[2][2];
  #pragma unroll
  for (int i = 0; i < 2; ++i)
    #pragma unroll
    for (int kd = 0; kd < 2; ++kd)
      qf[i][kd] = *(const bf16x8*)(Qh + (size_t)(qt + i * 16 + cl) * 64 + kd * 32 + g * 8);

  f32x4 o[2][4];
  f32x4 lacc[2];
  #pragma unroll
  for (int i = 0; i < 2; ++i) {
    lacc[i] = (f32x4){0.f, 0.f, 0.f, 0.f};
    #pragma unroll
    for (int jd = 0; jd < 4; ++jd) o[i][jd] = (f32x4){0.f, 0.f, 0.f, 0.f};
  }
  float m[2] = {-1e30f, -1e30f};

  bf16x8 ones;
  #pragma unroll
  for (int e = 0; e < 8; ++e) ones[e] = (__bf16)1.0f;

  short* P = (short*)Ps[wid];
  // hoisted P write offsets (loop-invariant): row = i*16+cl, granule swizzled
  int pwo[2][4];
  #pragma unroll
  for (int i = 0; i < 2; ++i)
    #pragma unroll
    for (int j = 0; j < 4; ++j)
      pwo[i][j] = (i * 16 + cl) * 64 + (((j * 2 + (g >> 1)) ^ (cl & 7)) * 8) + (g & 1) * 4;

  for (int kv = 0; kv < 4096; kv += 64) {
    __syncthreads();
    #pragma unroll
    for (int t = 0; t < 2; ++t) {
      stage_gran(Kh + (size_t)kv * 64, 64, Ks, (wid * 2 + t) * 64, lane);
      stage_gran(Vh + kv, 4096, Vs, (wid * 2 + t) * 64, lane);
    }
    __syncthreads();

    // S^T = K Q^T  (exp2 domain): s[i][j], lane holds q=cl, kv=j*16+g*4+r
    f32x4 s[2][4];
    #pragma unroll
    for (int i = 0; i < 2; ++i)
      #pragma unroll
      for (int j = 0; j < 4; ++j) s[i][j] = (f32x4){0.f, 0.f, 0.f, 0.f};
    #pragma unroll
    for (int kd = 0; kd < 2; ++kd) {
      bf16x8 kf[4];
      #pragma unroll
      for (int j = 0; j < 4; ++j) kf[j] = frag_ld(Ks + j * 16 * 64, lane, kd);
      #pragma unroll
      for (int i = 0; i < 2; ++i)
        #pragma unroll
        for (int j = 0; j < 4; ++j)
          s[i][j] = __builtin_amdgcn_mfma_f32_16x16x32_bf16(kf[j], qf[i][kd], s[i][j], 0, 0, 0);
    }

    // lane-local max over the 16 kv this lane holds per i
    float lmax[2];
    #pragma unroll
    for (int i = 0; i < 2; ++i) {
      float a = fmaxf(fmaxf(s[i][0][0], s[i][0][1]), fmaxf(s[i][0][2], s[i][0][3]));
      float b = fmaxf(fmaxf(s[i][1][0], s[i][1][1]), fmaxf(s[i][1][2], s[i][1][3]));
      float c = fmaxf(fmaxf(s[i][2][0], s[i][2][1]), fmaxf(s[i][2][2], s[i][2][3]));
      float d = fmaxf(fmaxf(s[i][3][0], s[i][3][1]), fmaxf(s[i][3][2], s[i][3][3]));
      lmax[i] = fmaxf(fmaxf(a, b), fmaxf(c, d));
    }

    // defer-max: slow path only when some row's max grew past m+THR
    if (!__all((lmax[0] <= m[0] + THR) && (lmax[1] <= m[1] + THR))) {
      #pragma unroll
      for (int i = 0; i < 2; ++i) {
        float mx = lmax[i];
        mx = fmaxf(mx, __shfl_xor(mx, 16));
        mx = fmaxf(mx, __shfl_xor(mx, 32));
        float mnew = fmaxf(m[i], mx);
        float corr = exp2f(m[i] - mnew);
        m[i] = mnew;
        // transfer corr from softmax domain (q=cl) to output domain (q=g*4+r)
        float c[4];
        #pragma unroll
        for (int r = 0; r < 4; ++r) c[r] = __shfl(corr, (g << 2) | r);
        #pragma unroll
        for (int jd = 0; jd < 4; ++jd)
          #pragma unroll
          for (int r = 0; r < 4; ++r) o[i][jd][r] *= c[r];
        #pragma unroll
        for (int r = 0; r < 4; ++r) lacc[i][r] *= c[r];
      }
    }

    // p = exp2(s - m) -> bf16 packed write (ds_write_b64, hoisted addrs)
    #pragma unroll
    for (int i = 0; i < 2; ++i)
      #pragma unroll
      for (int j = 0; j < 4; ++j) {
        bf16x4 pw;
        #pragma unroll
        for (int r = 0; r < 4; ++r) pw[r] = (__bf16)exp2f(s[i][j][r] - m[i]);
        *(bf16x4*)(P + pwo[i][j]) = pw;
      }

    // O += P @ V ; l += P @ ones
    #pragma unroll
    for (int kk = 0; kk < 2; ++kk) {
      bf16x8 pf[2], vf[4];
      #pragma unroll
      for (int i = 0; i < 2; ++i) pf[i] = frag_ld(P + i * 16 * 64, lane, kk);
      #pragma unroll
      for (int jd = 0; jd < 4; ++jd) vf[jd] = frag_ld(Vs + jd * 16 * 64, lane, kk);
      #pragma unroll
      for (int i = 0; i < 2; ++i)
        lacc[i] = __builtin_amdgcn_mfma_f32_16x16x32_bf16(pf[i], ones, lacc[i], 0, 0, 0);
      #pragma unroll
      for (int i = 0; i < 2; ++i)
        #pragma unroll
        for (int jd = 0; jd < 4; ++jd)
          o[i][jd] = __builtin_amdgcn_mfma_f32_16x16x32_bf16(pf[i], vf[jd], o[i][jd], 0, 0, 0);
    }
  }

  // epilogue: O/l -> attn_out bf16 [b][n][h*64+d]; o rows = g*4+r, cols = cl
  const int b = bh >> 3, h = bh & 7;
  #pragma unroll
  for (int i = 0; i < 2; ++i) {
    #pragma unroll
    for (int r = 0; r < 4; ++r) {
      const float inv = 1.f / lacc[i][r];
      const int n = qt + i * 16 + g * 4 + r;
      #pragma unroll
      for (int jd = 0; jd < 4; ++jd) {
        const int d = h * 64 + jd * 16 + cl;
        AOut[((size_t)b * 4096 + n) * 512 + d] = f2bf(o[i][jd][r] * inv);
      }
    }
  }
}

// ---------------- launcher ----------------

extern "C" void kernel_launch(void* const* d_in, const int* in_sizes, int n_in,
                              void* d_out, int out_size, void* d_ws, size_t ws_size,
                              hipStream_t stream) {
  const float* x    = (const float*)d_in[0];
  const float* Wqkv = (const float*)d_in[1];
  const float* bqkv = (const float*)d_in[2];
  const float* Wout = (const float*)d_in[3];
  const float* bout = (const float*)d_in[4];
  float* out = (float*)d_out;

  short* ws   = (short*)d_ws;
  short* xb   = ws;                       // 8192*512
  short* Wqt  = xb + 8192 * 512;          // 1536*512  (W_qkv^T)
  short* Wot  = Wqt + 1536 * 512;         // 512*512   (W_out^T)
  short* Qb   = Wot + 512 * 512;          // 16*4096*64 (scaled)
  short* Kb   = Qb + 16 * 4096 * 64;
  short* Vtb  = Kb + 16 * 4096 * 64;      // per-head V^T [bh][64][4096]
  short* AOut = Vtb + 16 * 4096 * 64;     // 8192*512

  hipLaunchKernelGGL(cvt_k, dim3(8192 * 512 / 4 / 256), dim3(256), 0, stream,
                     x, xb, 8192 * 512 / 4);
  hipLaunchKernelGGL(tcvt_k, dim3(1536 / 32, 512 / 32), dim3(256), 0, stream,
                     Wqkv, Wqt, 512, 1536);
  hipLaunchKernelGGL(tcvt_k, dim3(512 / 32, 512 / 32), dim3(256), 0, stream,
                     Wout, Wot, 512, 512);
  hipLaunchKernelGGL(gemm_k<0>, dim3(8192 / 128, 1536 / 128), dim3(256), 0, stream,
                     xb, Wqt, bqkv, (float*)nullptr, Qb, Kb, Vtb, 8192, 1536, 512);
  hipLaunchKernelGGL(attn_k, dim3(4096 / 128, 16), dim3(256), 0, stream,
                     Qb, Kb, Vtb, AOut);
  hipLaunchKernelGGL(gemm_k<1>, dim3(8192 / 128, 512 / 128), dim3(256), 0, stream,
                     AOut, Wot, bout, out, (short*)nullptr, (short*)nullptr, (short*)nullptr,
                     8192, 512, 512);
}

// Round 5
// 242.610 us; speedup vs baseline: 1.4356x; 1.0344x over previous
//
#include <hip/hip_runtime.h>

typedef __attribute__((ext_vector_type(4))) float f32x4;
typedef __attribute__((ext_vector_type(8))) __bf16 bf16x8;
typedef __attribute__((ext_vector_type(4))) __bf16 bf16x4;
typedef __attribute__((ext_vector_type(4))) short s16x4;

#define DEVI static __device__ __forceinline__

#define LOG2E 1.44269504088896340736f
#define THR 10.0f

// float -> bf16 (RNE) via hardware cvt
DEVI short f2bf(float f) {
  return __builtin_bit_cast(short, (__bf16)f);
}

// async global->LDS, 16B per lane; dest = uniform base + lane*16
DEVI void gll16(const short* gsrc, short* ldst) {
  __builtin_amdgcn_global_load_lds(
      (const __attribute__((address_space(1))) unsigned*)gsrc,
      (__attribute__((address_space(3))) unsigned*)ldst, 16, 0, 0);
}

// Stage one 1KB chunk (64 granules of 16B) of a [rows][64-short] LDS tile.
// LDS granule q holds global chunk k8 = (q&7) ^ (row&7) of row q>>3
// (pre-swizzled source, linear LDS dest — conflict-free swizzled reads).
DEVI void stage_gran(const short* g, int ldRow, short* lds, int p, int lane) {
  int q = p + lane;
  int row = q >> 3;
  int k8 = (q & 7) ^ (row & 7);
  gll16(g + (size_t)row * ldRow + k8 * 8, lds + (size_t)p * 8);
}

// Read a 16x32 MFMA operand fragment from a swizzled tile.
// lane&15 = row-in-block (M/N index), k-chunk = kk*4 + (lane>>4).
DEVI bf16x8 frag_ld(const short* base, int lane, int kk) {
  int r = lane & 15;
  int chunk = (kk * 4 + (lane >> 4)) ^ (r & 7);
  return *(const bf16x8*)(base + r * 64 + chunk * 8);
}

// ---------------- converts ----------------

__global__ void cvt_k(const float* __restrict__ in, short* __restrict__ out, int n4) {
  int i = blockIdx.x * blockDim.x + threadIdx.x;
  if (i < n4) {
    f32x4 v = *(const f32x4*)(in + (size_t)i * 4);
    s16x4 o;
    #pragma unroll
    for (int j = 0; j < 4; ++j) o[j] = f2bf(v[j]);
    *(s16x4*)(out + (size_t)i * 4) = o;
  }
}

// transpose + convert: in fp32 [R][C] -> out bf16 [C][R]
__global__ void tcvt_k(const float* __restrict__ in, short* __restrict__ out, int R, int C) {
  __shared__ float t[32][33];
  const int bx = blockIdx.x * 32;   // C offset
  const int by = blockIdx.y * 32;   // R offset
  const int lx = threadIdx.x & 31, ly = threadIdx.x >> 5;
  #pragma unroll
  for (int rr = ly; rr < 32; rr += 8)
    t[rr][lx] = in[(size_t)(by + rr) * C + bx + lx];
  __syncthreads();
  #pragma unroll
  for (int cc = ly; cc < 32; cc += 8)
    out[(size_t)(bx + cc) * R + by + lx] = f2bf(t[lx][cc]);
}

// ---------------- GEMM: C[M][N] = A[M][K] @ Bt[N][K]^T + bias ----------------

template <int EPI>
__global__ __launch_bounds__(256, 3)
void gemm_k(const short* __restrict__ A, const short* __restrict__ Bt,
            const float* __restrict__ bias, float* __restrict__ outF,
            short* __restrict__ Qb, short* __restrict__ Kb, short* __restrict__ Vtb,
            int M, int N, int K) {
  __shared__ __align__(16) short As[128 * 64];
  __shared__ __align__(16) short Bs[128 * 64];
  const int lane = threadIdx.x & 63;
  const int wid  = threadIdx.x >> 6;
  const int mt = blockIdx.x * 128;
  const int nt = blockIdx.y * 128;
  const int wm = (wid >> 1) * 64;
  const int wn = (wid & 1) * 64;

  f32x4 acc[4][4];
  #pragma unroll
  for (int i = 0; i < 4; ++i)
    #pragma unroll
    for (int j = 0; j < 4; ++j) acc[i][j] = (f32x4){0.f, 0.f, 0.f, 0.f};

  const short* Atile = A + (size_t)mt * K;
  const short* Btile = Bt + (size_t)nt * K;
  const int nkt = K >> 6;

  for (int kt = 0; kt < nkt; ++kt) {
    __syncthreads();
    #pragma unroll
    for (int i = 0; i < 4; ++i) {
      stage_gran(Atile + kt * 64, K, As, (wid * 4 + i) * 64, lane);
      stage_gran(Btile + kt * 64, K, Bs, (wid * 4 + i) * 64, lane);
    }
    __syncthreads();
    #pragma unroll
    for (int kk = 0; kk < 2; ++kk) {
      bf16x8 af[4], bfr[4];
      #pragma unroll
      for (int i = 0; i < 4; ++i) af[i] = frag_ld(As + (wm + i * 16) * 64, lane, kk);
      #pragma unroll
      for (int j = 0; j < 4; ++j) bfr[j] = frag_ld(Bs + (wn + j * 16) * 64, lane, kk);
      #pragma unroll
      for (int i = 0; i < 4; ++i)
        #pragma unroll
        for (int j = 0; j < 4; ++j)
          acc[i][j] = __builtin_amdgcn_mfma_f32_16x16x32_bf16(af[i], bfr[j], acc[i][j], 0, 0, 0);
    }
  }

  const int rbase = (lane >> 4) * 4;
  const int cl = lane & 15;
  #pragma unroll
  for (int i = 0; i < 4; ++i) {
    #pragma unroll
    for (int j = 0; j < 4; ++j) {
      const int col = nt + wn + j * 16 + cl;
      const float bv = bias[col];
      #pragma unroll
      for (int r = 0; r < 4; ++r) {
        const int row = mt + wm + i * 16 + rbase + r;
        float v = acc[i][j][r] + bv;
        if (EPI == 1) {
          outF[(size_t)row * N + col] = v;
        } else {
          const int which = col >> 9;  // 0=Q 1=K 2=V
          const int d = col & 511;
          const int h = d >> 6, hd = d & 63;
          const int b = row >> 12, n = row & 4095;
          const int bh = b * 8 + h;
          if (which == 0)
            Qb[((size_t)bh * 4096 + n) * 64 + hd] = f2bf(v * (0.125f * LOG2E));
          else if (which == 1)
            Kb[((size_t)bh * 4096 + n) * 64 + hd] = f2bf(v);
          else
            Vtb[((size_t)bh * 64 + hd) * 4096 + n] = f2bf(v);
        }
      }
    }
  }
}

// ---------------- flash attention (swapped QK^T, dbuf K/V, 4 wg/CU) --------
// grid (N/64, BH); 4 waves, each owns 16 q-rows. Q pre-scaled by 0.125*log2e.
// 2-phase pipeline: STAGE(next) issued before compute(cur); one barrier/tile.
// LDS = 2*8K (K) + 2*8K (V) + 4*2K (P) = 40KB -> 4 blocks/CU (160KB exactly).

__global__ __launch_bounds__(256, 4)
void attn_k(const short* __restrict__ Qb, const short* __restrict__ Kb,
            const short* __restrict__ Vtb, short* __restrict__ AOut) {
  __shared__ __align__(16) short Ks[2][64 * 64];  // [buf][kv][d]  swizzled
  __shared__ __align__(16) short Vs[2][64 * 64];  // [buf][d][kv]  swizzled
  __shared__ __align__(16) short Ps[4][16 * 64];  // per-wave P [q][kv] swizzled
  const int lane = threadIdx.x & 63;
  const int wid = threadIdx.x >> 6;
  const int bh = blockIdx.y;
  const int qt = blockIdx.x * 64 + wid * 16;      // this wave's 16 q-rows
  const short* Qh = Qb + (size_t)bh * 4096 * 64;
  const short* Kh = Kb + (size_t)bh * 4096 * 64;
  const short* Vh = Vtb + (size_t)bh * 64 * 4096;
  const int cl = lane & 15, g = lane >> 4;

  // Q fragments (B-operand of swapped QK^T): lane&15 = q-row
  bf16x8 qf[2];
  #pragma unroll
  for (int kd = 0; kd < 2; ++kd)
    qf[kd] = *(const bf16x8*)(Qh + (size_t)(qt + cl) * 64 + kd * 32 + g * 8);

  f32x4 o[4];
  f32x4 lacc = (f32x4){0.f, 0.f, 0.f, 0.f};
  #pragma unroll
  for (int jd = 0; jd < 4; ++jd) o[jd] = (f32x4){0.f, 0.f, 0.f, 0.f};
  float m = -1e30f;

  bf16x8 ones;
  #pragma unroll
  for (int e = 0; e < 8; ++e) ones[e] = (__bf16)1.0f;

  short* P = (short*)Ps[wid];
  // hoisted P write offsets (loop-invariant): row = cl, granule swizzled
  int pwo[4];
  #pragma unroll
  for (int j = 0; j < 4; ++j)
    pwo[j] = cl * 64 + (((j * 2 + (g >> 1)) ^ (cl & 7)) * 8) + (g & 1) * 4;

  // stage K/V tile at kv into buffer b (each wave stages 2 of 8 chunks each)
  auto STAGE = [&](int b, int kv) {
    #pragma unroll
    for (int t = 0; t < 2; ++t) {
      stage_gran(Kh + (size_t)kv * 64, 64, Ks[b], (wid * 2 + t) * 64, lane);
      stage_gran(Vh + kv, 4096, Vs[b], (wid * 2 + t) * 64, lane);
    }
  };

  STAGE(0, 0);
  __syncthreads();

  for (int t = 0; t < 64; ++t) {
    const int cur = t & 1;
    if (t < 63) STAGE(cur ^ 1, (t + 1) * 64);   // prefetch hides under compute

    // S^T = K Q^T  (exp2 domain): lane holds q=cl, kv=j*16+g*4+r
    f32x4 s[4];
    #pragma unroll
    for (int j = 0; j < 4; ++j) s[j] = (f32x4){0.f, 0.f, 0.f, 0.f};
    __builtin_amdgcn_s_setprio(1);
    #pragma unroll
    for (int kd = 0; kd < 2; ++kd) {
      bf16x8 kf[4];
      #pragma unroll
      for (int j = 0; j < 4; ++j) kf[j] = frag_ld(Ks[cur] + j * 16 * 64, lane, kd);
      #pragma unroll
      for (int j = 0; j < 4; ++j)
        s[j] = __builtin_amdgcn_mfma_f32_16x16x32_bf16(kf[j], qf[kd], s[j], 0, 0, 0);
    }
    __builtin_amdgcn_s_setprio(0);

    // lane-local max over the 16 kv this lane holds
    float a0 = fmaxf(fmaxf(s[0][0], s[0][1]), fmaxf(s[0][2], s[0][3]));
    float a1 = fmaxf(fmaxf(s[1][0], s[1][1]), fmaxf(s[1][2], s[1][3]));
    float a2 = fmaxf(fmaxf(s[2][0], s[2][1]), fmaxf(s[2][2], s[2][3]));
    float a3 = fmaxf(fmaxf(s[3][0], s[3][1]), fmaxf(s[3][2], s[3][3]));
    float lmax = fmaxf(fmaxf(a0, a1), fmaxf(a2, a3));

    // defer-max: slow path only when some row's max grew past m+THR
    if (!__all(lmax <= m + THR)) {
      float mx = lmax;
      mx = fmaxf(mx, __shfl_xor(mx, 16));
      mx = fmaxf(mx, __shfl_xor(mx, 32));
      float mnew = fmaxf(m, mx);
      float corr = exp2f(m - mnew);
      m = mnew;
      // transfer corr from softmax domain (q=cl) to output domain (q=g*4+r)
      float c[4];
      #pragma unroll
      for (int r = 0; r < 4; ++r) c[r] = __shfl(corr, (g << 2) | r);
      #pragma unroll
      for (int jd = 0; jd < 4; ++jd)
        #pragma unroll
        for (int r = 0; r < 4; ++r) o[jd][r] *= c[r];
      #pragma unroll
      for (int r = 0; r < 4; ++r) lacc[r] *= c[r];
    }

    // p = exp2(s - m) -> bf16 packed write (ds_write_b64, hoisted addrs)
    #pragma unroll
    for (int j = 0; j < 4; ++j) {
      bf16x4 pw;
      #pragma unroll
      for (int r = 0; r < 4; ++r) pw[r] = (__bf16)exp2f(s[j][r] - m);
      *(bf16x4*)(P + pwo[j]) = pw;
    }

    // O += P @ V ; l += P @ ones
    __builtin_amdgcn_s_setprio(1);
    #pragma unroll
    for (int kk = 0; kk < 2; ++kk) {
      bf16x8 pf = frag_ld(P, lane, kk);
      bf16x8 vf[4];
      #pragma unroll
      for (int jd = 0; jd < 4; ++jd) vf[jd] = frag_ld(Vs[cur] + jd * 16 * 64, lane, kk);
      lacc = __builtin_amdgcn_mfma_f32_16x16x32_bf16(pf, ones, lacc, 0, 0, 0);
      #pragma unroll
      for (int jd = 0; jd < 4; ++jd)
        o[jd] = __builtin_amdgcn_mfma_f32_16x16x32_bf16(pf, vf[jd], o[jd], 0, 0, 0);
    }
    __builtin_amdgcn_s_setprio(0);

    __syncthreads();  // drains prefetch vmcnt + all waves' ds_reads of cur
  }

  // epilogue: O/l -> attn_out bf16 [b][n][h*64+d]; o rows = g*4+r, cols = cl
  const int b = bh >> 3, h = bh & 7;
  #pragma unroll
  for (int r = 0; r < 4; ++r) {
    const float inv = 1.f / lacc[r];
    const int n = qt + g * 4 + r;
    #pragma unroll
    for (int jd = 0; jd < 4; ++jd) {
      const int d = h * 64 + jd * 16 + cl;
      AOut[((size_t)b * 4096 + n) * 512 + d] = f2bf(o[jd][r] * inv);
    }
  }
}

// ---------------- launcher ----------------

extern "C" void kernel_launch(void* const* d_in, const int* in_sizes, int n_in,
                              void* d_out, int out_size, void* d_ws, size_t ws_size,
                              hipStream_t stream) {
  const float* x    = (const float*)d_in[0];
  const float* Wqkv = (const float*)d_in[1];
  const float* bqkv = (const float*)d_in[2];
  const float* Wout = (const float*)d_in[3];
  const float* bout = (const float*)d_in[4];
  float* out = (float*)d_out;

  short* ws   = (short*)d_ws;
  short* xb   = ws;                       // 8192*512
  short* Wqt  = xb + 8192 * 512;          // 1536*512  (W_qkv^T)
  short* Wot  = Wqt + 1536 * 512;         // 512*512   (W_out^T)
  short* Qb   = Wot + 512 * 512;          // 16*4096*64 (scaled)
  short* Kb   = Qb + 16 * 4096 * 64;
  short* Vtb  = Kb + 16 * 4096 * 64;      // per-head V^T [bh][64][4096]
  short* AOut = Vtb + 16 * 4096 * 64;     // 8192*512

  hipLaunchKernelGGL(cvt_k, dim3(8192 * 512 / 4 / 256), dim3(256), 0, stream,
                     x, xb, 8192 * 512 / 4);
  hipLaunchKernelGGL(tcvt_k, dim3(1536 / 32, 512 / 32), dim3(256), 0, stream,
                     Wqkv, Wqt, 512, 1536);
  hipLaunchKernelGGL(tcvt_k, dim3(512 / 32, 512 / 32), dim3(256), 0, stream,
                     Wout, Wot, 512, 512);
  hipLaunchKernelGGL(gemm_k<0>, dim3(8192 / 128, 1536 / 128), dim3(256), 0, stream,
                     xb, Wqt, bqkv, (float*)nullptr, Qb, Kb, Vtb, 8192, 1536, 512);
  hipLaunchKernelGGL(attn_k, dim3(4096 / 64, 16), dim3(256), 0, stream,
                     Qb, Kb, Vtb, AOut);
  hipLaunchKernelGGL(gemm_k<1>, dim3(8192 / 128, 512 / 128), dim3(256), 0, stream,
                     AOut, Wot, bout, out, (short*)nullptr, (short*)nullptr, (short*)nullptr,
                     8192, 512, 512);
}